// Round 9
// baseline (171.755 us; speedup 1.0000x reference)
//
#include <hip/hip_runtime.h>

// Maxwell recurrence, v3: segmented pipeline with scalar affine carry.
//   gamma_{n+1} = (1-2*dt)*gamma + 2*dt*eps ;  sig = 2.5*eps - 2*gamma
// One 256-thread block per row; row split into 4 segments of 2048.
// Per segment: local compose -> wave scan -> cross-wave LDS scan ->
// replay+store; carry gamma across segments as a scalar affine apply.
// Next segment's loads are issued before current segment is consumed
// (register double buffer) so memory pressure is continuous.

constexpr int T_LEN   = 8192;
constexpr int THREADS = 256;
constexpr int SEGS    = 4;
constexpr int SEG_LEN = T_LEN / SEGS;       // 2048
constexpr int PER     = SEG_LEN / THREADS;  // 8 elems/thread/segment
constexpr float E_INF_C = 0.5f;
constexpr float E_C     = 2.0f;
constexpr float K_C     = 2.0f;             // E/ETA

__global__ __launch_bounds__(THREADS) void maxwell_seg_kernel(
    const float* __restrict__ eps, const float* __restrict__ dts,
    float* __restrict__ out)
{
    const int row  = blockIdx.x;
    const int tid  = threadIdx.x;
    const int lane = tid & 63;
    const int wave = tid >> 6;

    __shared__ float wA[4], wB[4];
    __shared__ float sA[THREADS], sB[THREADS];

    const long long rbase = (long long)row * T_LEN;

    float4 ev[2], dv[2], evn[2], dvn[2];

    // preload segment 0
    {
        const float4* p = reinterpret_cast<const float4*>(eps + rbase + tid * PER);
        const float4* q = reinterpret_cast<const float4*>(dts + rbase + tid * PER);
        ev[0] = p[0]; ev[1] = p[1];
        dv[0] = q[0]; dv[1] = q[1];
    }

    float carry = 0.f;   // gamma entering current segment (row start: 0)

#pragma unroll
    for (int s = 0; s < SEGS; ++s) {
        // issue next segment's loads before consuming current registers
        if (s + 1 < SEGS) {
            const long long nb = rbase + (long long)(s + 1) * SEG_LEN + tid * PER;
            const float4* p = reinterpret_cast<const float4*>(eps + nb);
            const float4* q = reinterpret_cast<const float4*>(dts + nb);
            evn[0] = p[0]; evn[1] = p[1];
            dvn[0] = q[0]; dvn[1] = q[1];
        }

        // ---- local affine compose of this thread's 8 elems: g -> a*g + b
        float a = 1.f, b = 0.f;
#pragma unroll
        for (int j = 0; j < 2; ++j) {
            const float4 e = ev[j], d = dv[j];
            float an, t;
            t = K_C * d.x; an = 1.f - t; b = an * b + t * e.x; a = an * a;
            t = K_C * d.y; an = 1.f - t; b = an * b + t * e.y; a = an * a;
            t = K_C * d.z; an = 1.f - t; b = an * b + t * e.z; a = an * a;
            t = K_C * d.w; an = 1.f - t; b = an * b + t * e.w; a = an * a;
        }

        // ---- wave-level inclusive scan
        float A = a, B = b;
#pragma unroll
        for (int off = 1; off < 64; off <<= 1) {
            float pA = __shfl_up(A, off, 64);
            float pB = __shfl_up(B, off, 64);
            if (lane >= off) { B = A * pB + B; A = A * pA; }
        }

        if (lane == 63) { wA[wave] = A; wB[wave] = B; }
        __syncthreads();

        // ---- cross-wave prefix (4 waves, unrolled broadcast reads)
        float pA = 1.f, pB = 0.f;
#pragma unroll
        for (int w = 0; w < 3; ++w) {
            if (w < wave) {
                const float aw = wA[w], bw = wB[w];
                pB = aw * pB + bw;
                pA = aw * pA;
            }
        }
        const float iA = A * pA;            // inclusive map of this thread
        const float iB = A * pB + B;
        sA[tid] = iA; sB[tid] = iB;
        __syncthreads();

        // exclusive prefix -> gamma at this thread's chunk start
        float gA = 1.f, gB = 0.f;
        if (tid != 0) { gA = sA[tid - 1]; gB = sB[tid - 1]; }
        float gamma = gA * carry + gB;

        // carry for next segment: inclusive map of last thread applied to carry
        const float cA = sA[THREADS - 1], cB = sB[THREADS - 1];
        carry = cA * carry + cB;

        // ---- replay the exact recurrence, store sigma
        float4* o = reinterpret_cast<float4*>(out + rbase + (long long)s * SEG_LEN + tid * PER);
#pragma unroll
        for (int j = 0; j < 2; ++j) {
            const float4 e = ev[j], d = dv[j];
            float4 sg;
            { float df = e.x - gamma; sg.x = E_INF_C * e.x + E_C * df; gamma += d.x * K_C * df; }
            { float df = e.y - gamma; sg.y = E_INF_C * e.y + E_C * df; gamma += d.y * K_C * df; }
            { float df = e.z - gamma; sg.z = E_INF_C * e.z + E_C * df; gamma += d.z * K_C * df; }
            { float df = e.w - gamma; sg.w = E_INF_C * e.w + E_C * df; gamma += d.w * K_C * df; }
            o[j] = sg;
        }

        // rotate double buffer
        if (s + 1 < SEGS) {
            ev[0] = evn[0]; ev[1] = evn[1];
            dv[0] = dvn[0]; dv[1] = dvn[1];
        }
        // No extra barrier needed: next wA write (pre-sync1') races only with
        // this segment's wA reads, which complete before sync2 above.
    }
}

extern "C" void kernel_launch(void* const* d_in, const int* in_sizes, int n_in,
                              void* d_out, int out_size, void* d_ws, size_t ws_size,
                              hipStream_t stream) {
    const float* eps = (const float*)d_in[0];
    const float* dts = (const float*)d_in[1];
    float* out = (float*)d_out;
    const int total = in_sizes[0];          // B * T
    const int nrows = total / T_LEN;        // 2048
    maxwell_seg_kernel<<<nrows, THREADS, 0, stream>>>(eps, dts, out);
}